// Round 1
// baseline (2467.075 us; speedup 1.0000x reference)
//
#include <hip/hip_runtime.h>
#include <math.h>

#define HID 64

// ---------------- degree / norm ----------------
__global__ void k_deg_init(float* deg, int n) {
    int i = blockIdx.x * blockDim.x + threadIdx.x;
    if (i < n) deg[i] = 1.0f;  // self-loop
}

__global__ void k_deg_accum(const int* __restrict__ col, float* deg, int E) {
    int e = blockIdx.x * blockDim.x + threadIdx.x;
    if (e < E) atomicAdd(&deg[col[e]], 1.0f);
}

__global__ void k_dinv(float* deg, int n) {
    int i = blockIdx.x * blockDim.x + threadIdx.x;
    if (i < n) {
        float d = deg[i];
        deg[i] = (d > 0.0f) ? rsqrtf(d) : 0.0f;
    }
}

// ---------------- matmul x[N,K] @ W[K,64] -> out[N,64] ----------------
// block (64,8): 8 nodes per block, 64 output channels per thread-x
__global__ void k_mm1(const float* __restrict__ x, const float* __restrict__ W,
                      float* __restrict__ out, int n, int K) {
    __shared__ float xs[8][304];
    int j = threadIdx.x, y = threadIdx.y;
    int node = blockIdx.x * 8 + y;
    for (int k = j; k < K; k += 64)
        xs[y][k] = (node < n) ? x[(size_t)node * K + k] : 0.0f;
    __syncthreads();
    if (node < n) {
        float acc = 0.0f;
        for (int k = 0; k < K; ++k)
            acc = fmaf(xs[y][k], W[k * HID + j], acc);
        out[(size_t)node * HID + j] = acc;
    }
}

// h[N,64] @ W[64,64] -> out[N,64], W staged in LDS
__global__ void k_mm2(const float* __restrict__ h, const float* __restrict__ W,
                      float* __restrict__ out, int n) {
    __shared__ float sW[HID * HID];
    __shared__ float xs[8][HID];
    int j = threadIdx.x, y = threadIdx.y;
    int tid = y * 64 + j;
    for (int t = tid; t < HID * HID; t += 512) sW[t] = W[t];
    int node = blockIdx.x * 8 + y;
    xs[y][j] = (node < n) ? h[(size_t)node * HID + j] : 0.0f;
    __syncthreads();
    if (node < n) {
        float acc = 0.0f;
        for (int k = 0; k < HID; ++k)
            acc = fmaf(xs[y][k], sW[k * HID + j], acc);
        out[(size_t)node * HID + j] = acc;
    }
}

// ---------------- aggregation ----------------
// dst[i][j] = src[i][j] * dinv[i]^2   (self-loop term; also fully initializes dst)
__global__ void k_selfloop(const float* __restrict__ src, const float* __restrict__ dinv,
                           float* __restrict__ dst, int n) {
    int tid = blockIdx.x * blockDim.x + threadIdx.x;
    int i = tid >> 6;
    if (i < n) {
        float d = dinv[i];
        dst[tid] = src[tid] * d * d;
    }
}

// one 64-lane group per edge: lane j handles channel j
__global__ void k_scatter(const int* __restrict__ row, const int* __restrict__ col,
                          const float* __restrict__ dinv, const float* __restrict__ src,
                          float* __restrict__ dst, int E) {
    int tid = blockIdx.x * blockDim.x + threadIdx.x;
    int e = tid >> 6, j = tid & 63;
    if (e < E) {
        int r = row[e], c = col[e];
        float nrm = dinv[r] * dinv[c];
        atomicAdd(&dst[(size_t)c * HID + j], src[(size_t)r * HID + j] * nrm);
    }
}

__global__ void k_bias_relu(float* buf, const float* __restrict__ b, int total) {
    int tid = blockIdx.x * blockDim.x + threadIdx.x;
    if (tid < total) {
        int j = tid & 63;
        float v = buf[tid] + b[j];
        buf[tid] = v > 0.0f ? v : 0.0f;
    }
}

// ---------------- pooling ----------------
__global__ void k_pool_init(float* p, int total) {
    int tid = blockIdx.x * blockDim.x + threadIdx.x;
    if (tid < total) p[tid] = 0.0f;
}

__global__ void k_pool_accum(const float* __restrict__ h, const int* __restrict__ batch,
                             const int* __restrict__ num_entity,
                             float* ent_sum, float* all_sum, float* ent_cnt, float* node_cnt,
                             int n) {
    int tid = blockIdx.x * blockDim.x + threadIdx.x;
    int i = tid >> 6, j = tid & 63;
    if (i < n) {
        int g = batch[i];
        float v = h[tid];
        atomicAdd(&all_sum[g * HID + j], v);
        bool mask = i < num_entity[g];
        if (mask) atomicAdd(&ent_sum[g * HID + j], v);
        if (j == 0) {
            atomicAdd(&node_cnt[g], 1.0f);
            if (mask) atomicAdd(&ent_cnt[g], 1.0f);
        }
    }
}

// ---------------- head: pooled @ Wlin + blin, log_softmax ----------------
__global__ void k_final(const float* __restrict__ ent_sum, const float* __restrict__ all_sum,
                        const float* __restrict__ ent_cnt, const float* __restrict__ node_cnt,
                        const float* __restrict__ Wlin, const float* __restrict__ blin,
                        float* __restrict__ out, int ncls) {
    int g = blockIdx.x, j = threadIdx.x;
    __shared__ float pooled[HID];
    __shared__ float logits[32];
    float ec = ent_cnt[g];
    float p;
    if (ec > 0.0f)
        p = ent_sum[g * HID + j] / (ec + 1e-6f);
    else
        p = all_sum[g * HID + j] / node_cnt[g];
    pooled[j] = p;
    __syncthreads();
    if (j < ncls) {
        float acc = blin[j];
        for (int k = 0; k < HID; ++k)
            acc = fmaf(pooled[k], Wlin[k * ncls + j], acc);
        logits[j] = acc;
    }
    __syncthreads();
    if (j < ncls) {
        float m = -INFINITY;
        for (int c = 0; c < ncls; ++c) m = fmaxf(m, logits[c]);
        float s = 0.0f;
        for (int c = 0; c < ncls; ++c) s += expf(logits[c] - m);
        out[g * ncls + j] = logits[j] - m - logf(s);
    }
}

extern "C" void kernel_launch(void* const* d_in, const int* in_sizes, int n_in,
                              void* d_out, int out_size, void* d_ws, size_t ws_size,
                              hipStream_t stream) {
    const float* x          = (const float*)d_in[0];
    const int*   ei         = (const int*)d_in[1];
    const int*   batch      = (const int*)d_in[2];
    const int*   num_entity = (const int*)d_in[3];
    const float* W1         = (const float*)d_in[4];
    const float* b1         = (const float*)d_in[5];
    const float* W2         = (const float*)d_in[6];
    const float* b2         = (const float*)d_in[7];
    const float* Wlin       = (const float*)d_in[8];
    const float* blin       = (const float*)d_in[9];
    float* out = (float*)d_out;

    int N = in_sizes[2];
    int E = in_sizes[1] / 2;
    int K = in_sizes[0] / N;      // 300
    int G = in_sizes[3];
    int NCLS = in_sizes[9];

    const int* row = ei;          // source
    const int* col = ei + E;      // target

    float* ws    = (float*)d_ws;
    float* dinv  = ws;                          // [N]
    float* bufA  = ws + N;                      // [N,64]
    float* bufB  = bufA + (size_t)N * HID;      // [N,64]
    float* ent_sum  = bufB + (size_t)N * HID;   // [G,64]
    float* all_sum  = ent_sum + (size_t)G * HID;// [G,64]
    float* ent_cnt  = all_sum + (size_t)G * HID;// [G]
    float* node_cnt = ent_cnt + G;              // [G]

    int total = N * HID;

    // degrees -> dinv
    k_deg_init<<<(N + 255) / 256, 256, 0, stream>>>(dinv, N);
    k_deg_accum<<<(E + 255) / 256, 256, 0, stream>>>(col, dinv, E);
    k_dinv<<<(N + 255) / 256, 256, 0, stream>>>(dinv, N);

    dim3 mmblk(64, 8);
    // layer 1
    k_mm1<<<(N + 7) / 8, mmblk, 0, stream>>>(x, W1, bufA, N, K);
    k_selfloop<<<(total + 255) / 256, 256, 0, stream>>>(bufA, dinv, bufB, N);
    {
        long long t = (long long)E * HID;
        k_scatter<<<(int)((t + 255) / 256), 256, 0, stream>>>(row, col, dinv, bufA, bufB, E);
    }
    k_bias_relu<<<(total + 255) / 256, 256, 0, stream>>>(bufB, b1, total);

    // layer 2
    k_mm2<<<(N + 7) / 8, mmblk, 0, stream>>>(bufB, W2, bufA, N);
    k_selfloop<<<(total + 255) / 256, 256, 0, stream>>>(bufA, dinv, bufB, N);
    {
        long long t = (long long)E * HID;
        k_scatter<<<(int)((t + 255) / 256), 256, 0, stream>>>(row, col, dinv, bufA, bufB, E);
    }
    k_bias_relu<<<(total + 255) / 256, 256, 0, stream>>>(bufB, b2, total);

    // pooling
    int pool_total = 2 * G * HID + 2 * G;
    k_pool_init<<<(pool_total + 255) / 256, 256, 0, stream>>>(ent_sum, pool_total);
    k_pool_accum<<<(total + 255) / 256, 256, 0, stream>>>(bufB, batch, num_entity,
                                                          ent_sum, all_sum, ent_cnt, node_cnt, N);

    // head
    k_final<<<G, HID, 0, stream>>>(ent_sum, all_sum, ent_cnt, node_cnt, Wlin, blin, out, NCLS);
}

// Round 3
// 802.234 us; speedup vs baseline: 3.0753x; 3.0753x over previous
//
#include <hip/hip_runtime.h>
#include <math.h>

#define HID 64

// ---------------- CSR build ----------------
__global__ void k_hist(const int* __restrict__ col, int* __restrict__ cnt, int E) {
    int e = blockIdx.x * blockDim.x + threadIdx.x;
    if (e < E) atomicAdd(&cnt[col[e]], 1);
}

__global__ void k_dinvk(const int* __restrict__ cnt, float* __restrict__ dinv, int n) {
    int i = blockIdx.x * blockDim.x + threadIdx.x;
    if (i < n) dinv[i] = rsqrtf((float)(cnt[i] + 1));  // +1 self-loop, always > 0
}

#define SBS 1024
__global__ void k_scan1(const int* __restrict__ cnt, int* __restrict__ excl,
                        int* __restrict__ bsum, int n) {
    __shared__ int s[SBS];
    int tid = threadIdx.x;
    int i = blockIdx.x * SBS + tid;
    int v = (i < n) ? cnt[i] : 0;
    s[tid] = v;
    __syncthreads();
    for (int off = 1; off < SBS; off <<= 1) {
        int t = (tid >= off) ? s[tid - off] : 0;
        __syncthreads();
        s[tid] += t;
        __syncthreads();
    }
    if (i < n) excl[i] = s[tid] - v;          // block-local exclusive
    if (tid == SBS - 1) bsum[blockIdx.x] = s[tid];
}

__global__ void k_scan2(int* bsum, int nb) {
    int run = 0;
    for (int b = 0; b < nb; ++b) { int t = bsum[b]; bsum[b] = run; run += t; }
}

__global__ void k_scan3(int* __restrict__ rowptr, int* __restrict__ cursor,
                        const int* __restrict__ bsum, int n, int E) {
    int i = blockIdx.x * blockDim.x + threadIdx.x;
    if (i < n) {
        int v = rowptr[i] + bsum[i / SBS];
        rowptr[i] = v;
        cursor[i] = v;
    }
    if (i == 0) rowptr[n] = E;
}

__global__ void k_fill(const int* __restrict__ row, const int* __restrict__ col,
                       int* cursor, int* __restrict__ srcs, int E) {
    int e = blockIdx.x * blockDim.x + threadIdx.x;
    if (e < E) {
        int c = col[e];
        int p = atomicAdd(&cursor[c], 1);
        srcs[p] = row[e];
    }
}

// ---------------- GEMM: out[i][c] = dinv[i] * sum_k A[i][k] W[k][c] ----------------
// 64x64 output tile, 256 threads, 4x4 register blocking, K staged in 32-chunks.
__global__ __launch_bounds__(256) void k_gemm(const float* __restrict__ A,
                                              const float* __restrict__ W,
                                              const float* __restrict__ dinv,
                                              float* __restrict__ out,
                                              int n, int K) {
    __shared__ float sA[32][64];   // [kk][m] (transposed)
    __shared__ float sW[32][64];   // [kk][c]
    int t = threadIdx.x;
    int m0 = blockIdx.x * 64;
    int tm = t >> 4, tn = t & 15;
    float acc[4][4] = {};

    int arow = t >> 2;             // 0..63
    int akb  = (t & 3) * 8;        // 0,8,16,24
    int wrow = t >> 3;             // 0..31
    int wcb  = (t & 7) * 8;        // 0..56

    for (int k0 = 0; k0 < K; k0 += 32) {
        // stage A (transposed into sA)
        int node = m0 + arow;
        if (node < n && k0 + akb + 7 < K) {
            const float4* p = (const float4*)(A + (size_t)node * K + k0 + akb);
            float4 v0 = p[0], v1 = p[1];
            sA[akb + 0][arow] = v0.x; sA[akb + 1][arow] = v0.y;
            sA[akb + 2][arow] = v0.z; sA[akb + 3][arow] = v0.w;
            sA[akb + 4][arow] = v1.x; sA[akb + 5][arow] = v1.y;
            sA[akb + 6][arow] = v1.z; sA[akb + 7][arow] = v1.w;
        } else {
            for (int u = 0; u < 8; ++u) {
                int k = k0 + akb + u;
                sA[akb + u][arow] = (node < n && k < K) ? A[(size_t)node * K + k] : 0.0f;
            }
        }
        // stage W
        {
            int k = k0 + wrow;
            if (k < K) {
                const float4* p = (const float4*)(W + (size_t)k * HID + wcb);
                *(float4*)&sW[wrow][wcb]     = p[0];
                *(float4*)&sW[wrow][wcb + 4] = p[1];
            } else {
                float4 z = {0.f, 0.f, 0.f, 0.f};
                *(float4*)&sW[wrow][wcb]     = z;
                *(float4*)&sW[wrow][wcb + 4] = z;
            }
        }
        __syncthreads();
        #pragma unroll
        for (int kk = 0; kk < 32; ++kk) {
            float4 av = *(const float4*)&sA[kk][tm * 4];
            float4 wv = *(const float4*)&sW[kk][tn * 4];
            const float* ap = &av.x;
            #pragma unroll
            for (int i = 0; i < 4; ++i) {
                float a = ap[i];
                acc[i][0] = fmaf(a, wv.x, acc[i][0]);
                acc[i][1] = fmaf(a, wv.y, acc[i][1]);
                acc[i][2] = fmaf(a, wv.z, acc[i][2]);
                acc[i][3] = fmaf(a, wv.w, acc[i][3]);
            }
        }
        __syncthreads();
    }
    #pragma unroll
    for (int i = 0; i < 4; ++i) {
        int node = m0 + tm * 4 + i;
        if (node < n) {
            float d = dinv[node];
            float4 o = { acc[i][0] * d, acc[i][1] * d, acc[i][2] * d, acc[i][3] * d };
            *(float4*)(out + (size_t)node * HID + tn * 4) = o;
        }
    }
}

// ---------------- gather aggregation (fused bias + relu) ----------------
// input "scaled" = dinv[i]*(h@W)[i]; output = relu(dinv[i]*(scaled[i]+sum_r scaled[r]) + b)
__global__ void k_agg(const float* __restrict__ scaled, const int* __restrict__ rowptr,
                      const int* __restrict__ srcs, const float* __restrict__ dinv,
                      const float* __restrict__ bias, float* __restrict__ out, int n) {
    int node = blockIdx.x * 4 + (threadIdx.x >> 6);
    int j = threadIdx.x & 63;
    if (node >= n) return;
    float a0 = scaled[(size_t)node * HID + j];   // self-loop term
    float a1 = 0.f, a2 = 0.f, a3 = 0.f;
    int s = rowptr[node], e = rowptr[node + 1];
    int k = s;
    for (; k + 3 < e; k += 4) {
        int r0 = srcs[k], r1 = srcs[k + 1], r2 = srcs[k + 2], r3 = srcs[k + 3];
        a0 += scaled[(size_t)r0 * HID + j];
        a1 += scaled[(size_t)r1 * HID + j];
        a2 += scaled[(size_t)r2 * HID + j];
        a3 += scaled[(size_t)r3 * HID + j];
    }
    for (; k < e; ++k) a0 += scaled[(size_t)srcs[k] * HID + j];
    float acc = (a0 + a1) + (a2 + a3);
    float v = fmaf(acc, dinv[node], bias[j]);
    out[(size_t)node * HID + j] = v > 0.f ? v : 0.f;
}

// ---------------- pooling (batch is sorted -> register accumulation per chunk) ----------------
#define PCHUNK 128
__global__ void k_pool(const float* __restrict__ h, const int* __restrict__ batch,
                       const int* __restrict__ ne_arr,
                       float* ent_sum, float* all_sum, float* ent_cnt, float* node_cnt,
                       int n) {
    int wave = blockIdx.x * (blockDim.x >> 6) + (threadIdx.x >> 6);
    int j = threadIdx.x & 63;
    int i0 = wave * PCHUNK;
    if (i0 >= n) return;
    int iend = min(i0 + PCHUNK, n);
    int g = batch[i0];
    int ne = ne_arr[g];
    float ea = 0.f, aa = 0.f, ec = 0.f, nc = 0.f;
    for (int i = i0; i < iend; ++i) {
        int gi = batch[i];
        if (gi != g) {
            atomicAdd(&all_sum[g * HID + j], aa);
            atomicAdd(&ent_sum[g * HID + j], ea);
            if (j == 0) { atomicAdd(&node_cnt[g], nc); atomicAdd(&ent_cnt[g], ec); }
            g = gi; ne = ne_arr[g];
            ea = aa = ec = nc = 0.f;
        }
        float v = h[(size_t)i * HID + j];
        aa += v; nc += 1.f;
        if (i < ne) { ea += v; ec += 1.f; }
    }
    atomicAdd(&all_sum[g * HID + j], aa);
    atomicAdd(&ent_sum[g * HID + j], ea);
    if (j == 0) { atomicAdd(&node_cnt[g], nc); atomicAdd(&ent_cnt[g], ec); }
}

// ---------------- head ----------------
__global__ void k_final(const float* __restrict__ ent_sum, const float* __restrict__ all_sum,
                        const float* __restrict__ ent_cnt, const float* __restrict__ node_cnt,
                        const float* __restrict__ Wlin, const float* __restrict__ blin,
                        float* __restrict__ out, int ncls) {
    int g = blockIdx.x, j = threadIdx.x;
    __shared__ float pooled[HID];
    __shared__ float logits[32];
    float ec = ent_cnt[g];
    float p;
    if (ec > 0.0f)
        p = ent_sum[g * HID + j] / (ec + 1e-6f);
    else
        p = all_sum[g * HID + j] / node_cnt[g];
    pooled[j] = p;
    __syncthreads();
    if (j < ncls) {
        float acc = blin[j];
        for (int k = 0; k < HID; ++k)
            acc = fmaf(pooled[k], Wlin[k * ncls + j], acc);
        logits[j] = acc;
    }
    __syncthreads();
    if (j < ncls) {
        float m = -INFINITY;
        for (int c = 0; c < ncls; ++c) m = fmaxf(m, logits[c]);
        float s = 0.0f;
        for (int c = 0; c < ncls; ++c) s += expf(logits[c] - m);
        out[g * ncls + j] = logits[j] - m - logf(s);
    }
}

extern "C" void kernel_launch(void* const* d_in, const int* in_sizes, int n_in,
                              void* d_out, int out_size, void* d_ws, size_t ws_size,
                              hipStream_t stream) {
    const float* x          = (const float*)d_in[0];
    const int*   ei         = (const int*)d_in[1];
    const int*   batch      = (const int*)d_in[2];
    const int*   num_entity = (const int*)d_in[3];
    const float* W1         = (const float*)d_in[4];
    const float* b1         = (const float*)d_in[5];
    const float* W2         = (const float*)d_in[6];
    const float* b2         = (const float*)d_in[7];
    const float* Wlin       = (const float*)d_in[8];
    const float* blin       = (const float*)d_in[9];
    float* out = (float*)d_out;

    int N = in_sizes[2];
    int E = in_sizes[1] / 2;
    int K = in_sizes[0] / N;      // 300
    int G = in_sizes[3];
    int NCLS = in_sizes[9];

    const int* row = ei;          // source
    const int* col = ei + E;      // target

    // ---- workspace layout (256 B aligned regions) ----
    char* wsb = (char*)d_ws;
    size_t off = 0;
    auto take = [&](size_t bytes) -> void* {
        void* p = wsb + off;
        off += (bytes + 255) & ~(size_t)255;
        return p;
    };
    int*   cnt      = (int*)take((size_t)N * 4);        // histogram, later cursor
    int*   rowptr   = (int*)take((size_t)(N + 1) * 4);
    float* dinv     = (float*)take((size_t)N * 4);
    int*   bsum     = (int*)take(1024 * 4);
    int*   srcs     = (int*)take((size_t)E * 4);
    float* bufA     = (float*)take((size_t)N * HID * 4);
    float* bufB     = (float*)take((size_t)N * HID * 4);
    float* ent_sum  = (float*)take((size_t)G * HID * 4);
    float* all_sum  = (float*)take((size_t)G * HID * 4);
    float* ent_cnt  = (float*)take((size_t)G * 4);
    float* node_cnt = (float*)take((size_t)G * 4);

    // ---- CSR build + degrees ----
    hipMemsetAsync(cnt, 0, (size_t)N * 4, stream);
    k_hist<<<(E + 255) / 256, 256, 0, stream>>>(col, cnt, E);
    k_dinvk<<<(N + 255) / 256, 256, 0, stream>>>(cnt, dinv, N);
    int NB = (N + SBS - 1) / SBS;
    k_scan1<<<NB, SBS, 0, stream>>>(cnt, rowptr, bsum, N);
    k_scan2<<<1, 1, 0, stream>>>(bsum, NB);
    k_scan3<<<(N + 255) / 256, 256, 0, stream>>>(rowptr, cnt /*cursor*/, bsum, N, E);
    k_fill<<<(E + 255) / 256, 256, 0, stream>>>(row, col, cnt, srcs, E);

    // ---- layer 1 ----
    k_gemm<<<(N + 63) / 64, 256, 0, stream>>>(x, W1, dinv, bufA, N, K);
    k_agg<<<(N + 3) / 4, 256, 0, stream>>>(bufA, rowptr, srcs, dinv, b1, bufB, N);
    // ---- layer 2 ----
    k_gemm<<<(N + 63) / 64, 256, 0, stream>>>(bufB, W2, dinv, bufA, N, HID);
    k_agg<<<(N + 3) / 4, 256, 0, stream>>>(bufA, rowptr, srcs, dinv, b2, bufB, N);

    // ---- pooling ----
    hipMemsetAsync(ent_sum, 0, ((size_t)2 * G * HID + 2 * G) * 4, stream);
    k_pool<<<(N + PCHUNK * 4 - 1) / (PCHUNK * 4), 256, 0, stream>>>(
        bufB, batch, num_entity, ent_sum, all_sum, ent_cnt, node_cnt, N);

    // ---- head ----
    k_final<<<G, HID, 0, stream>>>(ent_sum, all_sum, ent_cnt, node_cnt, Wlin, blin, out, NCLS);
}

// Round 5
// 606.424 us; speedup vs baseline: 4.0682x; 1.3229x over previous
//
#include <hip/hip_runtime.h>
#include <math.h>

#define HID 64
#define BKT_W 256          // nodes per bucket (power of 2)
#define BKT_SHIFT 8
#define MAX_BKT 512        // supports N <= 131072
#define EPB 4096           // edges per binA block

// ---------------- degree histogram ----------------
__global__ void k_hist(const int* __restrict__ col, int* __restrict__ cnt, int E) {
    int e = blockIdx.x * blockDim.x + threadIdx.x;
    if (e < E) atomicAdd(&cnt[col[e]], 1);
}

__global__ void k_dinvk(const int* __restrict__ cnt, float* __restrict__ dinv, int n) {
    int i = blockIdx.x * blockDim.x + threadIdx.x;
    if (i < n) dinv[i] = rsqrtf((float)(cnt[i] + 1));  // +1 self-loop, always > 0
}

// ---------------- scan (rowptr) ----------------
#define SBS 1024
__global__ void k_scan1(const int* __restrict__ cnt, int* __restrict__ excl,
                        int* __restrict__ bsum, int n) {
    __shared__ int s[SBS];
    int tid = threadIdx.x;
    int i = blockIdx.x * SBS + tid;
    int v = (i < n) ? cnt[i] : 0;
    s[tid] = v;
    __syncthreads();
    for (int off = 1; off < SBS; off <<= 1) {
        int t = (tid >= off) ? s[tid - off] : 0;
        __syncthreads();
        s[tid] += t;
        __syncthreads();
    }
    if (i < n) excl[i] = s[tid] - v;
    if (tid == SBS - 1) bsum[blockIdx.x] = s[tid];
}

__global__ void k_scan2(int* bsum, int nb) {
    int run = 0;
    for (int b = 0; b < nb; ++b) { int t = bsum[b]; bsum[b] = run; run += t; }
}

__global__ void k_scan3(int* __restrict__ rowptr, const int* __restrict__ bsum, int n, int E) {
    int i = blockIdx.x * blockDim.x + threadIdx.x;
    if (i < n) rowptr[i] += bsum[i / SBS];
    if (i == 0) rowptr[n] = E;
}

// ---------------- bucketed edge sort ----------------
__global__ void k_bcinit(const int* __restrict__ rowptr, int* __restrict__ bcursor,
                         int nbkt, int n) {
    int b = blockIdx.x * blockDim.x + threadIdx.x;
    if (b < nbkt) {
        int n0 = b << BKT_SHIFT;
        bcursor[b] = rowptr[n0 < n ? n0 : n];
    }
}

// pass A: bin edges into bucket-contiguous (col,row) pairs
__global__ __launch_bounds__(256) void k_binA(const int* __restrict__ row,
                                              const int* __restrict__ col,
                                              int* __restrict__ bcursor,
                                              int2* __restrict__ pairs,
                                              int E, int nbkt) {
    __shared__ int hist[MAX_BKT];
    __shared__ int base[MAX_BKT];
    int t = threadIdx.x;
    for (int b = t; b < nbkt; b += 256) hist[b] = 0;
    __syncthreads();
    int e0 = blockIdx.x * EPB;
    int myc[16], myr[16], myoff[16];
    #pragma unroll
    for (int i = 0; i < 16; ++i) {
        int e = e0 + t + i * 256;
        if (e < E) {
            myc[i] = col[e];
            myr[i] = row[e];
            myoff[i] = atomicAdd(&hist[myc[i] >> BKT_SHIFT], 1);
        }
    }
    __syncthreads();
    for (int b = t; b < nbkt; b += 256) {
        int h = hist[b];
        base[b] = h ? atomicAdd(&bcursor[b], h) : 0;
    }
    __syncthreads();
    #pragma unroll
    for (int i = 0; i < 16; ++i) {
        int e = e0 + t + i * 256;
        if (e < E) {
            int bk = myc[i] >> BKT_SHIFT;
            pairs[base[bk] + myoff[i]] = make_int2(myc[i], myr[i]);
        }
    }
}

// pass B: within each bucket, scatter rows to CSR positions (dst slice is L2-hot)
__global__ __launch_bounds__(256) void k_binB(const int2* __restrict__ pairs,
                                              const int* __restrict__ rowptr,
                                              int* __restrict__ srcs, int n) {
    __shared__ int lcur[BKT_W];
    int b = blockIdx.x, t = threadIdx.x;
    int n0 = b << BKT_SHIFT;
    int n1 = min(n0 + BKT_W, n);
    if (t < n1 - n0) lcur[t] = rowptr[n0 + t];
    int s0 = rowptr[n0], s1 = rowptr[n1];
    __syncthreads();
    for (int i = s0 + t; i < s1; i += 256) {
        int2 pr = pairs[i];
        int p = atomicAdd(&lcur[pr.x - n0], 1);
        srcs[p] = pr.y;
    }
}

// ---------------- GEMM: out[i][c] = dinv[i] * sum_k A[i][k] W[k][c] ----------------
__global__ __launch_bounds__(256) void k_gemm(const float* __restrict__ A,
                                              const float* __restrict__ W,
                                              const float* __restrict__ dinv,
                                              float* __restrict__ out,
                                              int n, int K) {
    __shared__ float sA[32][64];
    __shared__ float sW[32][64];
    int t = threadIdx.x;
    int m0 = blockIdx.x * 64;
    int tm = t >> 4, tn = t & 15;
    float acc[4][4] = {};

    int arow = t >> 2;
    int akb  = (t & 3) * 8;
    int wrow = t >> 3;
    int wcb  = (t & 7) * 8;

    for (int k0 = 0; k0 < K; k0 += 32) {
        int node = m0 + arow;
        if (node < n && k0 + akb + 7 < K) {
            const float4* p = (const float4*)(A + (size_t)node * K + k0 + akb);
            float4 v0 = p[0], v1 = p[1];
            sA[akb + 0][arow] = v0.x; sA[akb + 1][arow] = v0.y;
            sA[akb + 2][arow] = v0.z; sA[akb + 3][arow] = v0.w;
            sA[akb + 4][arow] = v1.x; sA[akb + 5][arow] = v1.y;
            sA[akb + 6][arow] = v1.z; sA[akb + 7][arow] = v1.w;
        } else {
            for (int u = 0; u < 8; ++u) {
                int k = k0 + akb + u;
                sA[akb + u][arow] = (node < n && k < K) ? A[(size_t)node * K + k] : 0.0f;
            }
        }
        {
            int k = k0 + wrow;
            if (k < K) {
                const float4* p = (const float4*)(W + (size_t)k * HID + wcb);
                *(float4*)&sW[wrow][wcb]     = p[0];
                *(float4*)&sW[wrow][wcb + 4] = p[1];
            } else {
                float4 z = {0.f, 0.f, 0.f, 0.f};
                *(float4*)&sW[wrow][wcb]     = z;
                *(float4*)&sW[wrow][wcb + 4] = z;
            }
        }
        __syncthreads();
        #pragma unroll
        for (int kk = 0; kk < 32; ++kk) {
            float4 av = *(const float4*)&sA[kk][tm * 4];
            float4 wv = *(const float4*)&sW[kk][tn * 4];
            const float* ap = &av.x;
            #pragma unroll
            for (int i = 0; i < 4; ++i) {
                float a = ap[i];
                acc[i][0] = fmaf(a, wv.x, acc[i][0]);
                acc[i][1] = fmaf(a, wv.y, acc[i][1]);
                acc[i][2] = fmaf(a, wv.z, acc[i][2]);
                acc[i][3] = fmaf(a, wv.w, acc[i][3]);
            }
        }
        __syncthreads();
    }
    #pragma unroll
    for (int i = 0; i < 4; ++i) {
        int node = m0 + tm * 4 + i;
        if (node < n) {
            float d = dinv[node];
            float4 o = { acc[i][0] * d, acc[i][1] * d, acc[i][2] * d, acc[i][3] * d };
            *(float4*)(out + (size_t)node * HID + tn * 4) = o;
        }
    }
}

// ---------------- gather aggregation (fused bias + relu) ----------------
__global__ void k_agg(const float* __restrict__ scaled, const int* __restrict__ rowptr,
                      const int* __restrict__ srcs, const float* __restrict__ dinv,
                      const float* __restrict__ bias, float* __restrict__ out, int n) {
    int node = blockIdx.x * 4 + (threadIdx.x >> 6);
    int j = threadIdx.x & 63;
    if (node >= n) return;
    float a0 = scaled[(size_t)node * HID + j];   // self-loop term
    float a1 = 0.f, a2 = 0.f, a3 = 0.f;
    int s = rowptr[node], e = rowptr[node + 1];
    int k = s;
    for (; k + 3 < e; k += 4) {
        int r0 = srcs[k], r1 = srcs[k + 1], r2 = srcs[k + 2], r3 = srcs[k + 3];
        a0 += scaled[(size_t)r0 * HID + j];
        a1 += scaled[(size_t)r1 * HID + j];
        a2 += scaled[(size_t)r2 * HID + j];
        a3 += scaled[(size_t)r3 * HID + j];
    }
    for (; k < e; ++k) a0 += scaled[(size_t)srcs[k] * HID + j];
    float acc = (a0 + a1) + (a2 + a3);
    float v = fmaf(acc, dinv[node], bias[j]);
    out[(size_t)node * HID + j] = v > 0.f ? v : 0.f;
}

// ---------------- pooling ----------------
#define PCHUNK 128
__global__ void k_pool(const float* __restrict__ h, const int* __restrict__ batch,
                       const int* __restrict__ ne_arr,
                       float* ent_sum, float* all_sum, float* ent_cnt, float* node_cnt,
                       int n) {
    int wave = blockIdx.x * (blockDim.x >> 6) + (threadIdx.x >> 6);
    int j = threadIdx.x & 63;
    int i0 = wave * PCHUNK;
    if (i0 >= n) return;
    int iend = min(i0 + PCHUNK, n);
    int g = batch[i0];
    int ne = ne_arr[g];
    float ea = 0.f, aa = 0.f, ec = 0.f, nc = 0.f;
    for (int i = i0; i < iend; ++i) {
        int gi = batch[i];
        if (gi != g) {
            atomicAdd(&all_sum[g * HID + j], aa);
            atomicAdd(&ent_sum[g * HID + j], ea);
            if (j == 0) { atomicAdd(&node_cnt[g], nc); atomicAdd(&ent_cnt[g], ec); }
            g = gi; ne = ne_arr[g];
            ea = aa = ec = nc = 0.f;
        }
        float v = h[(size_t)i * HID + j];
        aa += v; nc += 1.f;
        if (i < ne) { ea += v; ec += 1.f; }
    }
    atomicAdd(&all_sum[g * HID + j], aa);
    atomicAdd(&ent_sum[g * HID + j], ea);
    if (j == 0) { atomicAdd(&node_cnt[g], nc); atomicAdd(&ent_cnt[g], ec); }
}

// ---------------- head ----------------
__global__ void k_final(const float* __restrict__ ent_sum, const float* __restrict__ all_sum,
                        const float* __restrict__ ent_cnt, const float* __restrict__ node_cnt,
                        const float* __restrict__ Wlin, const float* __restrict__ blin,
                        float* __restrict__ out, int ncls) {
    int g = blockIdx.x, j = threadIdx.x;
    __shared__ float pooled[HID];
    __shared__ float logits[32];
    float ec = ent_cnt[g];
    float p;
    if (ec > 0.0f)
        p = ent_sum[g * HID + j] / (ec + 1e-6f);
    else
        p = all_sum[g * HID + j] / node_cnt[g];
    pooled[j] = p;
    __syncthreads();
    if (j < ncls) {
        float acc = blin[j];
        for (int k = 0; k < HID; ++k)
            acc = fmaf(pooled[k], Wlin[k * ncls + j], acc);
        logits[j] = acc;
    }
    __syncthreads();
    if (j < ncls) {
        float m = -INFINITY;
        for (int c = 0; c < ncls; ++c) m = fmaxf(m, logits[c]);
        float s = 0.0f;
        for (int c = 0; c < ncls; ++c) s += expf(logits[c] - m);
        out[g * ncls + j] = logits[j] - m - logf(s);
    }
}

extern "C" void kernel_launch(void* const* d_in, const int* in_sizes, int n_in,
                              void* d_out, int out_size, void* d_ws, size_t ws_size,
                              hipStream_t stream) {
    const float* x          = (const float*)d_in[0];
    const int*   ei         = (const int*)d_in[1];
    const int*   batch      = (const int*)d_in[2];
    const int*   num_entity = (const int*)d_in[3];
    const float* W1         = (const float*)d_in[4];
    const float* b1         = (const float*)d_in[5];
    const float* W2         = (const float*)d_in[6];
    const float* b2         = (const float*)d_in[7];
    const float* Wlin       = (const float*)d_in[8];
    const float* blin       = (const float*)d_in[9];
    float* out = (float*)d_out;

    int N = in_sizes[2];
    int E = in_sizes[1] / 2;
    int K = in_sizes[0] / N;      // 300
    int G = in_sizes[3];
    int NCLS = in_sizes[9];

    const int* row = ei;          // source
    const int* col = ei + E;      // target

    // ---- workspace layout ----
    char* wsb = (char*)d_ws;
    size_t off = 0;
    auto take = [&](size_t bytes) -> void* {
        void* p = wsb + off;
        off += (bytes + 255) & ~(size_t)255;
        return p;
    };
    int*   cnt      = (int*)take((size_t)N * 4);
    int*   rowptr   = (int*)take((size_t)(N + 1) * 4);
    float* dinv     = (float*)take((size_t)N * 4);
    int*   bsum     = (int*)take(1024 * 4);
    int*   bcursor  = (int*)take(MAX_BKT * 4);
    int*   srcs     = (int*)take((size_t)E * 4);
    float* bufA     = (float*)take((size_t)N * HID * 4);
    float* bufB     = (float*)take((size_t)N * HID * 4);
    float* ent_sum  = (float*)take((size_t)G * HID * 4);
    float* all_sum  = (float*)take((size_t)G * HID * 4);
    float* ent_cnt  = (float*)take((size_t)G * 4);
    float* node_cnt = (float*)take((size_t)G * 4);

    int2* pairs = (int2*)bufA;   // E*8 bytes = N*HID*4 bytes; free until k_gemm

    int nbkt = (N + BKT_W - 1) >> BKT_SHIFT;

    // ---- CSR build + degrees ----
    hipMemsetAsync(cnt, 0, (size_t)N * 4, stream);
    k_hist<<<(E + 255) / 256, 256, 0, stream>>>(col, cnt, E);
    k_dinvk<<<(N + 255) / 256, 256, 0, stream>>>(cnt, dinv, N);
    int NB = (N + SBS - 1) / SBS;
    k_scan1<<<NB, SBS, 0, stream>>>(cnt, rowptr, bsum, N);
    k_scan2<<<1, 1, 0, stream>>>(bsum, NB);
    k_scan3<<<(N + 255) / 256, 256, 0, stream>>>(rowptr, bsum, N, E);
    k_bcinit<<<(nbkt + 255) / 256, 256, 0, stream>>>(rowptr, bcursor, nbkt, N);
    k_binA<<<(E + EPB - 1) / EPB, 256, 0, stream>>>(row, col, bcursor, pairs, E, nbkt);
    k_binB<<<nbkt, 256, 0, stream>>>(pairs, rowptr, srcs, N);

    // ---- layer 1 ----
    k_gemm<<<(N + 63) / 64, 256, 0, stream>>>(x, W1, dinv, bufA, N, K);
    k_agg<<<(N + 3) / 4, 256, 0, stream>>>(bufA, rowptr, srcs, dinv, b1, bufB, N);
    // ---- layer 2 ----
    k_gemm<<<(N + 63) / 64, 256, 0, stream>>>(bufB, W2, dinv, bufA, N, HID);
    k_agg<<<(N + 3) / 4, 256, 0, stream>>>(bufA, rowptr, srcs, dinv, b2, bufB, N);

    // ---- pooling ----
    hipMemsetAsync(ent_sum, 0, ((size_t)2 * G * HID + 2 * G) * 4, stream);
    k_pool<<<(N + PCHUNK * 4 - 1) / (PCHUNK * 4), 256, 0, stream>>>(
        bufB, batch, num_entity, ent_sum, all_sum, ent_cnt, node_cnt, N);

    // ---- head ----
    k_final<<<G, HID, 0, stream>>>(ent_sum, all_sum, ent_cnt, node_cnt, Wlin, blin, out, NCLS);
}

// Round 6
// 505.489 us; speedup vs baseline: 4.8806x; 1.1997x over previous
//
#include <hip/hip_runtime.h>
#include <math.h>

#define HID 64
#define BKT_W 256          // nodes per bucket (power of 2)
#define BKT_SHIFT 8
#define MAX_BKT 512        // supports N <= 131072
#define EPB 4096           // edges per binA block
#define EPH 16384          // edges per bhist block

// ---------------- bucket-level histogram (391 counters, LDS-aggregated) ----------------
__global__ __launch_bounds__(256) void k_bhist(const int* __restrict__ col,
                                               int* __restrict__ bkt_cnt, int E, int nbkt) {
    __shared__ int h[MAX_BKT];
    int t = threadIdx.x;
    for (int b = t; b < nbkt; b += 256) h[b] = 0;
    __syncthreads();
    int e0 = blockIdx.x * EPH;
    int e1 = min(e0 + EPH, E);
    for (int e = e0 + t; e < e1; e += 256)
        atomicAdd(&h[col[e] >> BKT_SHIFT], 1);
    __syncthreads();
    for (int b = t; b < nbkt; b += 256)
        if (h[b]) atomicAdd(&bkt_cnt[b], h[b]);
}

// single-thread scan over buckets (nbkt ~ 391)
__global__ void k_bscan(const int* __restrict__ bkt_cnt, int* __restrict__ bkt_base, int nbkt) {
    int run = 0;
    for (int b = 0; b < nbkt; ++b) { bkt_base[b] = run; run += bkt_cnt[b]; }
    bkt_base[nbkt] = run;
}

__global__ void k_bcinit(const int* __restrict__ bkt_base, int* __restrict__ bcursor, int nbkt) {
    int b = blockIdx.x * blockDim.x + threadIdx.x;
    if (b < nbkt) bcursor[b] = bkt_base[b];
}

// pass A: bin edges into bucket-contiguous packed (row<<8 | col&255) words
__global__ __launch_bounds__(256) void k_binA(const int* __restrict__ row,
                                              const int* __restrict__ col,
                                              int* __restrict__ bcursor,
                                              unsigned int* __restrict__ pairs,
                                              int E, int nbkt) {
    __shared__ int hist[MAX_BKT];
    __shared__ int base[MAX_BKT];
    int t = threadIdx.x;
    for (int b = t; b < nbkt; b += 256) hist[b] = 0;
    __syncthreads();
    int e0 = blockIdx.x * EPB;
    int myc[16], myr[16], myoff[16];
    #pragma unroll
    for (int i = 0; i < 16; ++i) {
        int e = e0 + t + i * 256;
        if (e < E) {
            myc[i] = col[e];
            myr[i] = row[e];
            myoff[i] = atomicAdd(&hist[myc[i] >> BKT_SHIFT], 1);
        }
    }
    __syncthreads();
    for (int b = t; b < nbkt; b += 256) {
        int h = hist[b];
        base[b] = h ? atomicAdd(&bcursor[b], h) : 0;
    }
    __syncthreads();
    #pragma unroll
    for (int i = 0; i < 16; ++i) {
        int e = e0 + t + i * 256;
        if (e < E) {
            int bk = myc[i] >> BKT_SHIFT;
            pairs[base[bk] + myoff[i]] =
                ((unsigned int)myr[i] << BKT_SHIFT) | (unsigned int)(myc[i] & (BKT_W - 1));
        }
    }
}

// pass B: per bucket — per-node counts in LDS, LDS scan -> rowptr + dinv, then scatter srcs
__global__ __launch_bounds__(256) void k_binB(const unsigned int* __restrict__ pairs,
                                              const int* __restrict__ bkt_base,
                                              int* __restrict__ rowptr,
                                              int* __restrict__ srcs,
                                              float* __restrict__ dinv,
                                              int n, int E) {
    __shared__ int cnt[BKT_W];
    __shared__ int s[BKT_W];
    __shared__ int lcur[BKT_W];
    int b = blockIdx.x, t = threadIdx.x;
    int n0 = b << BKT_SHIFT;
    int n1 = min(n0 + BKT_W, n);
    int s0 = bkt_base[b], s1 = bkt_base[b + 1];
    cnt[t] = 0;
    __syncthreads();
    for (int i = s0 + t; i < s1; i += 256)
        atomicAdd(&cnt[pairs[i] & (BKT_W - 1)], 1);
    __syncthreads();
    int v = cnt[t];
    s[t] = v;
    __syncthreads();
    #pragma unroll
    for (int off = 1; off < BKT_W; off <<= 1) {
        int tv = (t >= off) ? s[t - off] : 0;
        __syncthreads();
        s[t] += tv;
        __syncthreads();
    }
    int ex = s[t] - v;                 // exclusive prefix within bucket
    if (t < n1 - n0) {
        rowptr[n0 + t] = s0 + ex;
        dinv[n0 + t] = rsqrtf((float)(v + 1));   // +1 self-loop
    }
    lcur[t] = s0 + ex;
    __syncthreads();
    for (int i = s0 + t; i < s1; i += 256) {
        unsigned int p = pairs[i];
        int pos = atomicAdd(&lcur[p & (BKT_W - 1)], 1);
        srcs[pos] = (int)(p >> BKT_SHIFT);
    }
    if (n1 == n && t == 0) rowptr[n] = E;
}

// ---------------- GEMM: out[i][c] = dinv[i] * sum_k A[i][k] W[k][c] ----------------
__global__ __launch_bounds__(256) void k_gemm(const float* __restrict__ A,
                                              const float* __restrict__ W,
                                              const float* __restrict__ dinv,
                                              float* __restrict__ out,
                                              int n, int K) {
    __shared__ float sA[32][64];
    __shared__ float sW[32][64];
    int t = threadIdx.x;
    int m0 = blockIdx.x * 64;
    int tm = t >> 4, tn = t & 15;
    float acc[4][4] = {};

    int arow = t >> 2;
    int akb  = (t & 3) * 8;
    int wrow = t >> 3;
    int wcb  = (t & 7) * 8;

    for (int k0 = 0; k0 < K; k0 += 32) {
        int node = m0 + arow;
        if (node < n && k0 + akb + 7 < K) {
            const float4* p = (const float4*)(A + (size_t)node * K + k0 + akb);
            float4 v0 = p[0], v1 = p[1];
            sA[akb + 0][arow] = v0.x; sA[akb + 1][arow] = v0.y;
            sA[akb + 2][arow] = v0.z; sA[akb + 3][arow] = v0.w;
            sA[akb + 4][arow] = v1.x; sA[akb + 5][arow] = v1.y;
            sA[akb + 6][arow] = v1.z; sA[akb + 7][arow] = v1.w;
        } else {
            for (int u = 0; u < 8; ++u) {
                int k = k0 + akb + u;
                sA[akb + u][arow] = (node < n && k < K) ? A[(size_t)node * K + k] : 0.0f;
            }
        }
        {
            int k = k0 + wrow;
            if (k < K) {
                const float4* p = (const float4*)(W + (size_t)k * HID + wcb);
                *(float4*)&sW[wrow][wcb]     = p[0];
                *(float4*)&sW[wrow][wcb + 4] = p[1];
            } else {
                float4 z = {0.f, 0.f, 0.f, 0.f};
                *(float4*)&sW[wrow][wcb]     = z;
                *(float4*)&sW[wrow][wcb + 4] = z;
            }
        }
        __syncthreads();
        #pragma unroll
        for (int kk = 0; kk < 32; ++kk) {
            float4 av = *(const float4*)&sA[kk][tm * 4];
            float4 wv = *(const float4*)&sW[kk][tn * 4];
            const float* ap = &av.x;
            #pragma unroll
            for (int i = 0; i < 4; ++i) {
                float a = ap[i];
                acc[i][0] = fmaf(a, wv.x, acc[i][0]);
                acc[i][1] = fmaf(a, wv.y, acc[i][1]);
                acc[i][2] = fmaf(a, wv.z, acc[i][2]);
                acc[i][3] = fmaf(a, wv.w, acc[i][3]);
            }
        }
        __syncthreads();
    }
    #pragma unroll
    for (int i = 0; i < 4; ++i) {
        int node = m0 + tm * 4 + i;
        if (node < n) {
            float d = dinv[node];
            float4 o = { acc[i][0] * d, acc[i][1] * d, acc[i][2] * d, acc[i][3] * d };
            *(float4*)(out + (size_t)node * HID + tn * 4) = o;
        }
    }
}

// ---------------- gather aggregation (fused bias + relu) ----------------
__global__ void k_agg(const float* __restrict__ scaled, const int* __restrict__ rowptr,
                      const int* __restrict__ srcs, const float* __restrict__ dinv,
                      const float* __restrict__ bias, float* __restrict__ out, int n) {
    int node = blockIdx.x * 4 + (threadIdx.x >> 6);
    int j = threadIdx.x & 63;
    if (node >= n) return;
    float a0 = scaled[(size_t)node * HID + j];   // self-loop term
    float a1 = 0.f, a2 = 0.f, a3 = 0.f;
    int s = rowptr[node], e = rowptr[node + 1];
    int k = s;
    for (; k + 3 < e; k += 4) {
        int r0 = srcs[k], r1 = srcs[k + 1], r2 = srcs[k + 2], r3 = srcs[k + 3];
        a0 += scaled[(size_t)r0 * HID + j];
        a1 += scaled[(size_t)r1 * HID + j];
        a2 += scaled[(size_t)r2 * HID + j];
        a3 += scaled[(size_t)r3 * HID + j];
    }
    for (; k < e; ++k) a0 += scaled[(size_t)srcs[k] * HID + j];
    float acc = (a0 + a1) + (a2 + a3);
    float v = fmaf(acc, dinv[node], bias[j]);
    out[(size_t)node * HID + j] = v > 0.f ? v : 0.f;
}

// ---------------- pooling ----------------
#define PCHUNK 128
__global__ void k_pool(const float* __restrict__ h, const int* __restrict__ batch,
                       const int* __restrict__ ne_arr,
                       float* ent_sum, float* all_sum, float* ent_cnt, float* node_cnt,
                       int n) {
    int wave = blockIdx.x * (blockDim.x >> 6) + (threadIdx.x >> 6);
    int j = threadIdx.x & 63;
    int i0 = wave * PCHUNK;
    if (i0 >= n) return;
    int iend = min(i0 + PCHUNK, n);
    int g = batch[i0];
    int ne = ne_arr[g];
    float ea = 0.f, aa = 0.f, ec = 0.f, nc = 0.f;
    for (int i = i0; i < iend; ++i) {
        int gi = batch[i];
        if (gi != g) {
            atomicAdd(&all_sum[g * HID + j], aa);
            atomicAdd(&ent_sum[g * HID + j], ea);
            if (j == 0) { atomicAdd(&node_cnt[g], nc); atomicAdd(&ent_cnt[g], ec); }
            g = gi; ne = ne_arr[g];
            ea = aa = ec = nc = 0.f;
        }
        float v = h[(size_t)i * HID + j];
        aa += v; nc += 1.f;
        if (i < ne) { ea += v; ec += 1.f; }
    }
    atomicAdd(&all_sum[g * HID + j], aa);
    atomicAdd(&ent_sum[g * HID + j], ea);
    if (j == 0) { atomicAdd(&node_cnt[g], nc); atomicAdd(&ent_cnt[g], ec); }
}

// ---------------- head ----------------
__global__ void k_final(const float* __restrict__ ent_sum, const float* __restrict__ all_sum,
                        const float* __restrict__ ent_cnt, const float* __restrict__ node_cnt,
                        const float* __restrict__ Wlin, const float* __restrict__ blin,
                        float* __restrict__ out, int ncls) {
    int g = blockIdx.x, j = threadIdx.x;
    __shared__ float pooled[HID];
    __shared__ float logits[32];
    float ec = ent_cnt[g];
    float p;
    if (ec > 0.0f)
        p = ent_sum[g * HID + j] / (ec + 1e-6f);
    else
        p = all_sum[g * HID + j] / node_cnt[g];
    pooled[j] = p;
    __syncthreads();
    if (j < ncls) {
        float acc = blin[j];
        for (int k = 0; k < HID; ++k)
            acc = fmaf(pooled[k], Wlin[k * ncls + j], acc);
        logits[j] = acc;
    }
    __syncthreads();
    if (j < ncls) {
        float m = -INFINITY;
        for (int c = 0; c < ncls; ++c) m = fmaxf(m, logits[c]);
        float s = 0.0f;
        for (int c = 0; c < ncls; ++c) s += expf(logits[c] - m);
        out[g * ncls + j] = logits[j] - m - logf(s);
    }
}

extern "C" void kernel_launch(void* const* d_in, const int* in_sizes, int n_in,
                              void* d_out, int out_size, void* d_ws, size_t ws_size,
                              hipStream_t stream) {
    const float* x          = (const float*)d_in[0];
    const int*   ei         = (const int*)d_in[1];
    const int*   batch      = (const int*)d_in[2];
    const int*   num_entity = (const int*)d_in[3];
    const float* W1         = (const float*)d_in[4];
    const float* b1         = (const float*)d_in[5];
    const float* W2         = (const float*)d_in[6];
    const float* b2         = (const float*)d_in[7];
    const float* Wlin       = (const float*)d_in[8];
    const float* blin       = (const float*)d_in[9];
    float* out = (float*)d_out;

    int N = in_sizes[2];
    int E = in_sizes[1] / 2;
    int K = in_sizes[0] / N;      // 300
    int G = in_sizes[3];
    int NCLS = in_sizes[9];

    const int* row = ei;          // source
    const int* col = ei + E;      // target

    // ---- workspace layout ----
    char* wsb = (char*)d_ws;
    size_t off = 0;
    auto take = [&](size_t bytes) -> void* {
        void* p = wsb + off;
        off += (bytes + 255) & ~(size_t)255;
        return p;
    };
    int*   rowptr   = (int*)take((size_t)(N + 1) * 4);
    float* dinv     = (float*)take((size_t)N * 4);
    int*   bkt_cnt  = (int*)take(MAX_BKT * 4);
    int*   bkt_base = (int*)take((MAX_BKT + 1) * 4);
    int*   bcursor  = (int*)take(MAX_BKT * 4);
    int*   srcs     = (int*)take((size_t)E * 4);
    float* bufA     = (float*)take((size_t)N * HID * 4);
    float* bufB     = (float*)take((size_t)N * HID * 4);
    float* ent_sum  = (float*)take((size_t)G * HID * 4);
    float* all_sum  = (float*)take((size_t)G * HID * 4);
    float* ent_cnt  = (float*)take((size_t)G * 4);
    float* node_cnt = (float*)take((size_t)G * 4);

    unsigned int* pairs = (unsigned int*)bufA;  // E*4 bytes <= N*HID*4; free until k_gemm

    int nbkt = (N + BKT_W - 1) >> BKT_SHIFT;

    // ---- CSR build (bucketed, no per-node global histogram) ----
    hipMemsetAsync(bkt_cnt, 0, (size_t)nbkt * 4, stream);
    k_bhist<<<(E + EPH - 1) / EPH, 256, 0, stream>>>(col, bkt_cnt, E, nbkt);
    k_bscan<<<1, 1, 0, stream>>>(bkt_cnt, bkt_base, nbkt);
    k_bcinit<<<(nbkt + 255) / 256, 256, 0, stream>>>(bkt_base, bcursor, nbkt);
    k_binA<<<(E + EPB - 1) / EPB, 256, 0, stream>>>(row, col, bcursor, pairs, E, nbkt);
    k_binB<<<nbkt, 256, 0, stream>>>(pairs, bkt_base, rowptr, srcs, dinv, N, E);

    // ---- layer 1 ----
    k_gemm<<<(N + 63) / 64, 256, 0, stream>>>(x, W1, dinv, bufA, N, K);
    k_agg<<<(N + 3) / 4, 256, 0, stream>>>(bufA, rowptr, srcs, dinv, b1, bufB, N);
    // ---- layer 2 ----
    k_gemm<<<(N + 63) / 64, 256, 0, stream>>>(bufB, W2, dinv, bufA, N, HID);
    k_agg<<<(N + 3) / 4, 256, 0, stream>>>(bufA, rowptr, srcs, dinv, b2, bufB, N);

    // ---- pooling ----
    hipMemsetAsync(ent_sum, 0, ((size_t)2 * G * HID + 2 * G) * 4, stream);
    k_pool<<<(N + PCHUNK * 4 - 1) / (PCHUNK * 4), 256, 0, stream>>>(
        bufB, batch, num_entity, ent_sum, all_sum, ent_cnt, node_cnt, N);

    // ---- head ----
    k_final<<<G, HID, 0, stream>>>(ent_sum, all_sum, ent_cnt, node_cnt, Wlin, blin, out, NCLS);
}

// Round 7
// 476.381 us; speedup vs baseline: 5.1788x; 1.0611x over previous
//
#include <hip/hip_runtime.h>
#include <math.h>

#define HID 64
#define BKT_W 256          // nodes per bucket (power of 2)
#define BKT_SHIFT 8
#define MAX_BKT 512        // supports N <= 131072
#define EPB 4096           // edges per binA block
#define EPH 16384          // edges per bhist block

__device__ __forceinline__ unsigned short f2bf(float x) {
    unsigned int b = __float_as_uint(x);
    unsigned int r = (b + 0x7FFFu + ((b >> 16) & 1u)) >> 16;   // RNE
    return (unsigned short)r;
}
__device__ __forceinline__ float bf2f(unsigned short u) {
    return __uint_as_float((unsigned int)u << 16);
}

// ---------------- bucket-level histogram ----------------
__global__ __launch_bounds__(256) void k_bhist(const int* __restrict__ col,
                                               int* __restrict__ bkt_cnt, int E, int nbkt) {
    __shared__ int h[MAX_BKT];
    int t = threadIdx.x;
    for (int b = t; b < nbkt; b += 256) h[b] = 0;
    __syncthreads();
    int e0 = blockIdx.x * EPH;
    int e1 = min(e0 + EPH, E);
    for (int e = e0 + t; e < e1; e += 256)
        atomicAdd(&h[col[e] >> BKT_SHIFT], 1);
    __syncthreads();
    for (int b = t; b < nbkt; b += 256)
        if (h[b]) atomicAdd(&bkt_cnt[b], h[b]);
}

__global__ void k_bscan(const int* __restrict__ bkt_cnt, int* __restrict__ bkt_base, int nbkt) {
    int run = 0;
    for (int b = 0; b < nbkt; ++b) { bkt_base[b] = run; run += bkt_cnt[b]; }
    bkt_base[nbkt] = run;
}

__global__ void k_bcinit(const int* __restrict__ bkt_base, int* __restrict__ bcursor, int nbkt) {
    int b = blockIdx.x * blockDim.x + threadIdx.x;
    if (b < nbkt) bcursor[b] = bkt_base[b];
}

// pass A: bin edges into bucket-contiguous packed (row<<8 | col&255) words
__global__ __launch_bounds__(256) void k_binA(const int* __restrict__ row,
                                              const int* __restrict__ col,
                                              int* __restrict__ bcursor,
                                              unsigned int* __restrict__ pairs,
                                              int E, int nbkt) {
    __shared__ int hist[MAX_BKT];
    __shared__ int base[MAX_BKT];
    int t = threadIdx.x;
    for (int b = t; b < nbkt; b += 256) hist[b] = 0;
    __syncthreads();
    int e0 = blockIdx.x * EPB;
    int myc[16], myr[16], myoff[16];
    #pragma unroll
    for (int i = 0; i < 16; ++i) {
        int e = e0 + t + i * 256;
        if (e < E) {
            myc[i] = col[e];
            myr[i] = row[e];
            myoff[i] = atomicAdd(&hist[myc[i] >> BKT_SHIFT], 1);
        }
    }
    __syncthreads();
    for (int b = t; b < nbkt; b += 256) {
        int h = hist[b];
        base[b] = h ? atomicAdd(&bcursor[b], h) : 0;
    }
    __syncthreads();
    #pragma unroll
    for (int i = 0; i < 16; ++i) {
        int e = e0 + t + i * 256;
        if (e < E) {
            int bk = myc[i] >> BKT_SHIFT;
            pairs[base[bk] + myoff[i]] =
                ((unsigned int)myr[i] << BKT_SHIFT) | (unsigned int)(myc[i] & (BKT_W - 1));
        }
    }
}

// pass B: per bucket — per-node counts in LDS, LDS scan -> rowptr + dinv, scatter srcs
__global__ __launch_bounds__(256) void k_binB(const unsigned int* __restrict__ pairs,
                                              const int* __restrict__ bkt_base,
                                              int* __restrict__ rowptr,
                                              int* __restrict__ srcs,
                                              float* __restrict__ dinv,
                                              int n, int E) {
    __shared__ int cnt[BKT_W];
    __shared__ int s[BKT_W];
    __shared__ int lcur[BKT_W];
    int b = blockIdx.x, t = threadIdx.x;
    int n0 = b << BKT_SHIFT;
    int n1 = min(n0 + BKT_W, n);
    int s0 = bkt_base[b], s1 = bkt_base[b + 1];
    cnt[t] = 0;
    __syncthreads();
    for (int i = s0 + t; i < s1; i += 256)
        atomicAdd(&cnt[pairs[i] & (BKT_W - 1)], 1);
    __syncthreads();
    int v = cnt[t];
    s[t] = v;
    __syncthreads();
    #pragma unroll
    for (int off = 1; off < BKT_W; off <<= 1) {
        int tv = (t >= off) ? s[t - off] : 0;
        __syncthreads();
        s[t] += tv;
        __syncthreads();
    }
    int ex = s[t] - v;
    if (t < n1 - n0) {
        rowptr[n0 + t] = s0 + ex;
        dinv[n0 + t] = rsqrtf((float)(v + 1));   // +1 self-loop
    }
    lcur[t] = s0 + ex;
    __syncthreads();
    for (int i = s0 + t; i < s1; i += 256) {
        unsigned int p = pairs[i];
        int pos = atomicAdd(&lcur[p & (BKT_W - 1)], 1);
        srcs[pos] = (int)(p >> BKT_SHIFT);
    }
    if (n1 == n && t == 0) rowptr[n] = E;
}

// ---------------- GEMM: outS[i][c] = bf16( dinv[i] * sum_k A[i][k] W[k][c] ) ----------------
__global__ __launch_bounds__(256) void k_gemm(const float* __restrict__ A,
                                              const float* __restrict__ W,
                                              const float* __restrict__ dinv,
                                              unsigned short* __restrict__ outS,
                                              int n, int K) {
    __shared__ float sA[32][64];
    __shared__ float sW[32][64];
    int t = threadIdx.x;
    int m0 = blockIdx.x * 64;
    int tm = t >> 4, tn = t & 15;
    float acc[4][4] = {};

    int arow = t >> 2;
    int akb  = (t & 3) * 8;
    int wrow = t >> 3;
    int wcb  = (t & 7) * 8;

    for (int k0 = 0; k0 < K; k0 += 32) {
        int node = m0 + arow;
        if (node < n && k0 + akb + 7 < K) {
            const float4* p = (const float4*)(A + (size_t)node * K + k0 + akb);
            float4 v0 = p[0], v1 = p[1];
            sA[akb + 0][arow] = v0.x; sA[akb + 1][arow] = v0.y;
            sA[akb + 2][arow] = v0.z; sA[akb + 3][arow] = v0.w;
            sA[akb + 4][arow] = v1.x; sA[akb + 5][arow] = v1.y;
            sA[akb + 6][arow] = v1.z; sA[akb + 7][arow] = v1.w;
        } else {
            for (int u = 0; u < 8; ++u) {
                int k = k0 + akb + u;
                sA[akb + u][arow] = (node < n && k < K) ? A[(size_t)node * K + k] : 0.0f;
            }
        }
        {
            int k = k0 + wrow;
            if (k < K) {
                const float4* p = (const float4*)(W + (size_t)k * HID + wcb);
                *(float4*)&sW[wrow][wcb]     = p[0];
                *(float4*)&sW[wrow][wcb + 4] = p[1];
            } else {
                float4 z = {0.f, 0.f, 0.f, 0.f};
                *(float4*)&sW[wrow][wcb]     = z;
                *(float4*)&sW[wrow][wcb + 4] = z;
            }
        }
        __syncthreads();
        #pragma unroll
        for (int kk = 0; kk < 32; ++kk) {
            float4 av = *(const float4*)&sA[kk][tm * 4];
            float4 wv = *(const float4*)&sW[kk][tn * 4];
            const float* ap = &av.x;
            #pragma unroll
            for (int i = 0; i < 4; ++i) {
                float a = ap[i];
                acc[i][0] = fmaf(a, wv.x, acc[i][0]);
                acc[i][1] = fmaf(a, wv.y, acc[i][1]);
                acc[i][2] = fmaf(a, wv.z, acc[i][2]);
                acc[i][3] = fmaf(a, wv.w, acc[i][3]);
            }
        }
        __syncthreads();
    }
    #pragma unroll
    for (int i = 0; i < 4; ++i) {
        int node = m0 + tm * 4 + i;
        if (node < n) {
            float d = dinv[node];
            ushort4 o;
            o.x = f2bf(acc[i][0] * d);
            o.y = f2bf(acc[i][1] * d);
            o.z = f2bf(acc[i][2] * d);
            o.w = f2bf(acc[i][3] * d);
            *(ushort4*)(outS + (size_t)node * HID + tn * 4) = o;
        }
    }
}

// ---------------- gather aggregation (bf16 messages, fused bias + relu) ----------------
__global__ void k_agg(const unsigned short* __restrict__ scaled, const int* __restrict__ rowptr,
                      const int* __restrict__ srcs, const float* __restrict__ dinv,
                      const float* __restrict__ bias, float* __restrict__ out, int n) {
    int node = blockIdx.x * 4 + (threadIdx.x >> 6);
    int j = threadIdx.x & 63;
    if (node >= n) return;
    float a0 = bf2f(scaled[(size_t)node * HID + j]);   // self-loop term
    float a1 = 0.f, a2 = 0.f, a3 = 0.f;
    int s = rowptr[node], e = rowptr[node + 1];
    int k = s;
    for (; k + 3 < e; k += 4) {
        int r0 = srcs[k], r1 = srcs[k + 1], r2 = srcs[k + 2], r3 = srcs[k + 3];
        a0 += bf2f(scaled[(size_t)r0 * HID + j]);
        a1 += bf2f(scaled[(size_t)r1 * HID + j]);
        a2 += bf2f(scaled[(size_t)r2 * HID + j]);
        a3 += bf2f(scaled[(size_t)r3 * HID + j]);
    }
    for (; k < e; ++k) a0 += bf2f(scaled[(size_t)srcs[k] * HID + j]);
    float acc = (a0 + a1) + (a2 + a3);
    float v = fmaf(acc, dinv[node], bias[j]);
    out[(size_t)node * HID + j] = v > 0.f ? v : 0.f;
}

// ---------------- pooling ----------------
#define PCHUNK 128
__global__ void k_pool(const float* __restrict__ h, const int* __restrict__ batch,
                       const int* __restrict__ ne_arr,
                       float* ent_sum, float* all_sum, float* ent_cnt, float* node_cnt,
                       int n) {
    int wave = blockIdx.x * (blockDim.x >> 6) + (threadIdx.x >> 6);
    int j = threadIdx.x & 63;
    int i0 = wave * PCHUNK;
    if (i0 >= n) return;
    int iend = min(i0 + PCHUNK, n);
    int g = batch[i0];
    int ne = ne_arr[g];
    float ea = 0.f, aa = 0.f, ec = 0.f, nc = 0.f;
    for (int i = i0; i < iend; ++i) {
        int gi = batch[i];
        if (gi != g) {
            atomicAdd(&all_sum[g * HID + j], aa);
            atomicAdd(&ent_sum[g * HID + j], ea);
            if (j == 0) { atomicAdd(&node_cnt[g], nc); atomicAdd(&ent_cnt[g], ec); }
            g = gi; ne = ne_arr[g];
            ea = aa = ec = nc = 0.f;
        }
        float v = h[(size_t)i * HID + j];
        aa += v; nc += 1.f;
        if (i < ne) { ea += v; ec += 1.f; }
    }
    atomicAdd(&all_sum[g * HID + j], aa);
    atomicAdd(&ent_sum[g * HID + j], ea);
    if (j == 0) { atomicAdd(&node_cnt[g], nc); atomicAdd(&ent_cnt[g], ec); }
}

// ---------------- head ----------------
__global__ void k_final(const float* __restrict__ ent_sum, const float* __restrict__ all_sum,
                        const float* __restrict__ ent_cnt, const float* __restrict__ node_cnt,
                        const float* __restrict__ Wlin, const float* __restrict__ blin,
                        float* __restrict__ out, int ncls) {
    int g = blockIdx.x, j = threadIdx.x;
    __shared__ float pooled[HID];
    __shared__ float logits[32];
    float ec = ent_cnt[g];
    float p;
    if (ec > 0.0f)
        p = ent_sum[g * HID + j] / (ec + 1e-6f);
    else
        p = all_sum[g * HID + j] / node_cnt[g];
    pooled[j] = p;
    __syncthreads();
    if (j < ncls) {
        float acc = blin[j];
        for (int k = 0; k < HID; ++k)
            acc = fmaf(pooled[k], Wlin[k * ncls + j], acc);
        logits[j] = acc;
    }
    __syncthreads();
    if (j < ncls) {
        float m = -INFINITY;
        for (int c = 0; c < ncls; ++c) m = fmaxf(m, logits[c]);
        float s = 0.0f;
        for (int c = 0; c < ncls; ++c) s += expf(logits[c] - m);
        out[g * ncls + j] = logits[j] - m - logf(s);
    }
}

extern "C" void kernel_launch(void* const* d_in, const int* in_sizes, int n_in,
                              void* d_out, int out_size, void* d_ws, size_t ws_size,
                              hipStream_t stream) {
    const float* x          = (const float*)d_in[0];
    const int*   ei         = (const int*)d_in[1];
    const int*   batch      = (const int*)d_in[2];
    const int*   num_entity = (const int*)d_in[3];
    const float* W1         = (const float*)d_in[4];
    const float* b1         = (const float*)d_in[5];
    const float* W2         = (const float*)d_in[6];
    const float* b2         = (const float*)d_in[7];
    const float* Wlin       = (const float*)d_in[8];
    const float* blin       = (const float*)d_in[9];
    float* out = (float*)d_out;

    int N = in_sizes[2];
    int E = in_sizes[1] / 2;
    int K = in_sizes[0] / N;      // 300
    int G = in_sizes[3];
    int NCLS = in_sizes[9];

    const int* row = ei;          // source
    const int* col = ei + E;      // target

    // ---- workspace layout ----
    char* wsb = (char*)d_ws;
    size_t off = 0;
    auto take = [&](size_t bytes) -> void* {
        void* p = wsb + off;
        off += (bytes + 255) & ~(size_t)255;
        return p;
    };
    int*   rowptr   = (int*)take((size_t)(N + 1) * 4);
    float* dinv     = (float*)take((size_t)N * 4);
    int*   bkt_cnt  = (int*)take(MAX_BKT * 4);
    int*   bkt_base = (int*)take((MAX_BKT + 1) * 4);
    int*   bcursor  = (int*)take(MAX_BKT * 4);
    int*   srcs     = (int*)take((size_t)E * 4);
    unsigned short* bufS = (unsigned short*)take((size_t)N * HID * 2);  // bf16 messages
    float* bufA     = (float*)take((size_t)N * HID * 4);                // fp32 h
    float* ent_sum  = (float*)take((size_t)G * HID * 4);
    float* all_sum  = (float*)take((size_t)G * HID * 4);
    float* ent_cnt  = (float*)take((size_t)G * 4);
    float* node_cnt = (float*)take((size_t)G * 4);

    // pairs (E*4 B) aliases bufS (N*HID*2 B, same size) — free until k_gemm layer 1
    unsigned int* pairs = (unsigned int*)bufS;

    int nbkt = (N + BKT_W - 1) >> BKT_SHIFT;

    // ---- CSR build (bucketed) ----
    hipMemsetAsync(bkt_cnt, 0, (size_t)nbkt * 4, stream);
    k_bhist<<<(E + EPH - 1) / EPH, 256, 0, stream>>>(col, bkt_cnt, E, nbkt);
    k_bscan<<<1, 1, 0, stream>>>(bkt_cnt, bkt_base, nbkt);
    k_bcinit<<<(nbkt + 255) / 256, 256, 0, stream>>>(bkt_base, bcursor, nbkt);
    k_binA<<<(E + EPB - 1) / EPB, 256, 0, stream>>>(row, col, bcursor, pairs, E, nbkt);
    k_binB<<<nbkt, 256, 0, stream>>>(pairs, bkt_base, rowptr, srcs, dinv, N, E);

    // ---- layer 1 ----
    k_gemm<<<(N + 63) / 64, 256, 0, stream>>>(x, W1, dinv, bufS, N, K);
    k_agg<<<(N + 3) / 4, 256, 0, stream>>>(bufS, rowptr, srcs, dinv, b1, bufA, N);
    // ---- layer 2 ----
    k_gemm<<<(N + 63) / 64, 256, 0, stream>>>(bufA, W2, dinv, bufS, N, HID);
    k_agg<<<(N + 3) / 4, 256, 0, stream>>>(bufS, rowptr, srcs, dinv, b2, bufA, N);

    // ---- pooling ----
    hipMemsetAsync(ent_sum, 0, ((size_t)2 * G * HID + 2 * G) * 4, stream);
    k_pool<<<(N + PCHUNK * 4 - 1) / (PCHUNK * 4), 256, 0, stream>>>(
        bufA, batch, num_entity, ent_sum, all_sum, ent_cnt, node_cnt, N);

    // ---- head ----
    k_final<<<G, HID, 0, stream>>>(ent_sum, all_sum, ent_cnt, node_cnt, Wlin, blin, out, NCLS);
}